// Round 1
// baseline (351.213 us; speedup 1.0000x reference)
//
#include <hip/hip_runtime.h>
#include <stdint.h>

#define NB    1024   // batch
#define NUM   512    // nodes
#define HD    64     // hidden/embedding dim
#define NE    4096   // edges
#define MAIN  10     // softmax segment
#define STR   72     // padded LDS row stride (shorts): breaks 32-bank power-of-2 stride

typedef __attribute__((ext_vector_type(8))) short short8;
typedef __attribute__((ext_vector_type(4))) float f32x4;

__device__ __forceinline__ short f2bf(float f) {
    uint32_t u = __float_as_uint(f);
    u += 0x7fffu + ((u >> 16) & 1u);   // round-to-nearest-even
    return (short)(u >> 16);
}
__device__ __forceinline__ float bf2f(short s) {
    return __uint_as_float(((uint32_t)(uint16_t)s) << 16);
}

// ---------------------------------------------------------------------------
// Prep 1: build degree -> dinv -> CSR (col-sorted, norm fused per edge).
// Single block, 512 threads. Runs every launch (ws is re-poisoned).
// ---------------------------------------------------------------------------
__global__ __launch_bounds__(512) void prep_csr(const int* __restrict__ erow,
                                                const int* __restrict__ ecol,
                                                int* __restrict__ ptr,
                                                int2* __restrict__ edges) {
    __shared__ int   sdeg[NUM];
    __shared__ int   sscan[NUM];
    __shared__ float sdinv[NUM];
    __shared__ int   curs[NUM];
    const int t = threadIdx.x;

    sdeg[t] = 0;
    __syncthreads();
    for (int e = t; e < NE; e += 512) atomicAdd(&sdeg[ecol[e]], 1);
    __syncthreads();
    {
        int d = sdeg[t];
        sdinv[t] = d > 0 ? rsqrtf((float)d) : 0.0f;
        sscan[t] = d;
    }
    __syncthreads();
    // Hillis-Steele inclusive scan over sscan
    for (int ofs = 1; ofs < NUM; ofs <<= 1) {
        int v = (t >= ofs) ? sscan[t - ofs] : 0;
        __syncthreads();
        sscan[t] += v;
        __syncthreads();
    }
    {
        int excl = (t == 0) ? 0 : sscan[t - 1];
        curs[t] = excl;
        ptr[t]  = excl;
        if (t == NUM - 1) ptr[NUM] = sscan[NUM - 1];
    }
    __syncthreads();
    for (int e = t; e < NE; e += 512) {
        int c = ecol[e], r = erow[e];
        int p = atomicAdd(&curs[c], 1);
        edges[p] = make_int2(r, __float_as_int(sdinv[r] * sdinv[c]));
    }
}

// ---------------------------------------------------------------------------
// Prep 2: E1 = emb @ W1  [512 x 64], stored bf16. Batch-independent, so layer-1
// GEMM collapses to an elementwise scale by x[b,n].
// ---------------------------------------------------------------------------
__global__ __launch_bounds__(256) void prep_e1(const float* __restrict__ emb,
                                               const float* __restrict__ W1,
                                               short* __restrict__ E1) {
    int i = blockIdx.x * 256 + threadIdx.x;   // 32768 total
    int n = i >> 6, j = i & 63;
    float acc = 0.0f;
    #pragma unroll
    for (int d = 0; d < HD; ++d) acc += emb[n * HD + d] * W1[d * HD + j];
    E1[i] = f2bf(acc);
}

// ---------------------------------------------------------------------------
// Fused main kernel: one block per batch element. All activations live in LDS
// (bf16, ping-pong bufA/bufB). Layers: scale -> agg -> GEMM(MFMA) -> agg ->
// dot(W3) -> agg -> softmax/sigmoid epilogue.
// ---------------------------------------------------------------------------
__global__ __launch_bounds__(512) void gcn_fused(
    const float* __restrict__ x,
    const float* __restrict__ W2, const float* __restrict__ b1,
    const float* __restrict__ b2, const float* __restrict__ W3,
    const float* __restrict__ b3,
    const int* __restrict__ ptr, const int2* __restrict__ edges,
    const short* __restrict__ E1,
    float* __restrict__ out)
{
    __shared__ short bufA[NUM * STR];   // 73728 B
    __shared__ short bufB[NUM * STR];   // 73728 B
    __shared__ short Wl[HD * HD];       // 8192 B  (W2 in bf16)
    __shared__ float sW3[HD];
    __shared__ float slog[NUM];
    __shared__ float sred[2];

    const int t    = threadIdx.x;
    const int b    = blockIdx.x;
    const int lane = t & 63;
    const int wave = __builtin_amdgcn_readfirstlane(t >> 6);  // 0..7, wave-uniform SGPR
    const int q    = lane >> 4;
    const int l15  = lane & 15;

    // ---- Stage 0: bufB = hW1 = x[b,n] * E1[n,:]; stage W2 -> Wl; W3 -> sW3
    for (int i = t; i < NUM * HD; i += 512) {
        int n = i >> 6, j = i & 63;
        bufB[n * STR + j] = f2bf(x[b * NUM + n] * bf2f(E1[i]));
    }
    for (int i = t; i < HD * HD; i += 512) Wl[i] = f2bf(W2[i]);
    if (t < HD) sW3[t] = W3[t];
    __syncthreads();

    // ---- Aggregation: OutBuf[c,:] = relu(bias + sum_e norm*In[src,:])
    auto do_agg = [&](const short* In, short* OutBuf, const float* bias) {
        float bj = bias[lane];
        for (int c = wave; c < NUM; c += 8) {
            int e0 = ptr[c], e1 = ptr[c + 1];
            float a0 = 0.f, a1 = 0.f, a2 = 0.f, a3 = 0.f;
            int e = e0;
            for (; e + 4 <= e1; e += 4) {
                int2 E0 = edges[e], E1e = edges[e + 1], E2 = edges[e + 2], E3 = edges[e + 3];
                a0 += __int_as_float(E0.y)  * bf2f(In[E0.x  * STR + lane]);
                a1 += __int_as_float(E1e.y) * bf2f(In[E1e.x * STR + lane]);
                a2 += __int_as_float(E2.y)  * bf2f(In[E2.x  * STR + lane]);
                a3 += __int_as_float(E3.y)  * bf2f(In[E3.x  * STR + lane]);
            }
            for (; e < e1; ++e) {
                int2 Ee = edges[e];
                a0 += __int_as_float(Ee.y) * bf2f(In[Ee.x * STR + lane]);
            }
            float v = (a0 + a1) + (a2 + a3) + bj;
            OutBuf[c * STR + lane] = f2bf(fmaxf(v, 0.0f));
        }
    };

    // ---- Layer 1 aggregate: bufB -> bufA  (h1)
    do_agg(bufB, bufA, b1);
    __syncthreads();

    // ---- Layer 2 GEMM (MFMA bf16): bufB = bufA @ W2
    {
        // B-operand fragments: B[k = q*8+j][n = l15] per 16x16x32 layout
        short8 bf[4][2];
        #pragma unroll
        for (int nt = 0; nt < 4; ++nt)
            #pragma unroll
            for (int ks = 0; ks < 2; ++ks) {
                short8 v;
                #pragma unroll
                for (int j = 0; j < 8; ++j)
                    v[j] = Wl[(ks * 32 + q * 8 + j) * HD + nt * 16 + l15];
                bf[nt][ks] = v;
            }
        f32x4 acc[4][4];
        #pragma unroll
        for (int mi = 0; mi < 4; ++mi)
            #pragma unroll
            for (int nt = 0; nt < 4; ++nt)
                acc[mi][nt] = (f32x4){0.f, 0.f, 0.f, 0.f};
        #pragma unroll
        for (int mi = 0; mi < 4; ++mi) {
            int rowi = (wave * 4 + mi) * 16 + l15;
            #pragma unroll
            for (int ks = 0; ks < 2; ++ks) {
                // A[m = l15][k = q*8+j]: contiguous 16B in k -> ds_read_b128
                short8 af = *(const short8*)&bufA[rowi * STR + ks * 32 + q * 8];
                #pragma unroll
                for (int nt = 0; nt < 4; ++nt)
                    acc[mi][nt] = __builtin_amdgcn_mfma_f32_16x16x32_bf16(
                        af, bf[nt][ks], acc[mi][nt], 0, 0, 0);
            }
        }
        // C/D layout: col = l15, row = q*4 + i  (within 16x16 tile)
        #pragma unroll
        for (int mi = 0; mi < 4; ++mi) {
            int mt = wave * 4 + mi;
            #pragma unroll
            for (int nt = 0; nt < 4; ++nt)
                #pragma unroll
                for (int i = 0; i < 4; ++i) {
                    int r = mt * 16 + q * 4 + i;
                    bufB[r * STR + nt * 16 + l15] = f2bf(acc[mi][nt][i]);
                }
        }
    }
    __syncthreads();

    // ---- Layer 2 aggregate: bufB -> bufA  (h2)
    do_agg(bufB, bufA, b2);
    __syncthreads();

    // ---- Layer 3: tvals[n] = h2[n,:] . W3  (store fp32 into bufB area)
    float* tvals = (float*)bufB;
    if (t < NUM) {
        float acc = 0.0f;
        #pragma unroll
        for (int d = 0; d < HD; ++d) acc += bf2f(bufA[t * STR + d]) * sW3[d];
        tvals[t] = acc;
    }
    __syncthreads();

    // ---- Layer 3 aggregate (scalar per node) -> logits
    if (t < NUM) {
        int e0 = ptr[t], e1 = ptr[t + 1];
        float a = 0.0f;
        for (int e = e0; e < e1; ++e) {
            int2 Ee = edges[e];
            a += __int_as_float(Ee.y) * tvals[Ee.x];
        }
        slog[t] = a + b3[0];
    }
    __syncthreads();

    // ---- Epilogue: softmax over [0,MAIN), sigmoid elsewhere
    if (t == 0) {
        float m = slog[0];
        for (int i = 1; i < MAIN; ++i) m = fmaxf(m, slog[i]);
        float s = 0.0f;
        for (int i = 0; i < MAIN; ++i) s += expf(slog[i] - m);
        sred[0] = m; sred[1] = s;
    }
    __syncthreads();
    if (t < NUM) {
        float l = slog[t];
        float o = (t < MAIN) ? expf(l - sred[0]) / sred[1]
                             : 1.0f / (1.0f + expf(-l));
        out[b * NUM + t] = o;
    }
}

// ---------------------------------------------------------------------------
extern "C" void kernel_launch(void* const* d_in, const int* in_sizes, int n_in,
                              void* d_out, int out_size, void* d_ws, size_t ws_size,
                              hipStream_t stream) {
    const float* x    = (const float*)d_in[0];
    const float* emb  = (const float*)d_in[1];
    const float* W1   = (const float*)d_in[2];
    const float* b1   = (const float*)d_in[3];
    const float* W2   = (const float*)d_in[4];
    const float* b2   = (const float*)d_in[5];
    const float* W3   = (const float*)d_in[6];
    const float* b3   = (const float*)d_in[7];
    const int*   erow = (const int*)d_in[8];
    const int*   ecol = (const int*)d_in[9];

    char* ws = (char*)d_ws;
    int*   ptr   = (int*)ws;                 // 513 ints  -> [0, 2052)
    int2*  edges = (int2*)(ws + 2176);       // 4096*8 B  -> [2176, 34944)
    short* E1    = (short*)(ws + 34944);     // 512*64*2  -> [34944, 100480)

    prep_csr<<<1, 512, 0, stream>>>(erow, ecol, ptr, edges);
    prep_e1<<<(NUM * HD) / 256, 256, 0, stream>>>(emb, W1, E1);
    gcn_fused<<<NB, 512, 0, stream>>>(x, W2, b1, b2, W3, b3, ptr, edges, E1,
                                      (float*)d_out);
}

// Round 2
// 269.358 us; speedup vs baseline: 1.3039x; 1.3039x over previous
//
#include <hip/hip_runtime.h>
#include <stdint.h>

#define NB    1024   // batch
#define NUM   512    // nodes
#define HD    64     // hidden dim
#define NE    4096   // edges
#define MAIN  10     // softmax segment
#define TSTR  520    // [dim][node] LDS stride (shorts): 520*2B=1040B -> bank 4(l15+q), uniform
#define NSTR  72     // [node][dim] LDS stride (shorts)
#define WSTR  72     // W2^T LDS stride

typedef __attribute__((ext_vector_type(8))) short short8;
typedef __attribute__((ext_vector_type(4))) short short4v;
typedef __attribute__((ext_vector_type(4))) float f32x4;

__device__ __forceinline__ short f2bf(float f) {
    uint32_t u = __float_as_uint(f);
    u += 0x7fffu + ((u >> 16) & 1u);   // RNE
    return (short)(u >> 16);
}
__device__ __forceinline__ float bf2f(short s) {
    return __uint_as_float(((uint32_t)(uint16_t)s) << 16);
}

// ---------------------------------------------------------------------------
// K1: blocks 0..511 zero Sf (dense fp32 S staging); block 512 computes dinv.
// ---------------------------------------------------------------------------
__global__ __launch_bounds__(512) void prep_zero_dinv(const int* __restrict__ ecol,
                                                      float* __restrict__ Sf,
                                                      float* __restrict__ dinv) {
    const int b = blockIdx.x, t = threadIdx.x;
    if (b < 512) {
        Sf[b * 512 + t] = 0.0f;
    } else {
        __shared__ int sdeg[NUM];
        sdeg[t] = 0;
        __syncthreads();
        for (int e = t; e < NE; e += 512) atomicAdd(&sdeg[ecol[e]], 1);
        __syncthreads();
        int d = sdeg[t];
        dinv[t] = d > 0 ? rsqrtf((float)d) : 0.0f;
    }
}

// ---------------------------------------------------------------------------
// K2: scatter edge norms into dense Sf[c][r] (+= handles duplicate edges).
// ---------------------------------------------------------------------------
__global__ __launch_bounds__(512) void prep_scatter(const int* __restrict__ erow,
                                                    const int* __restrict__ ecol,
                                                    const float* __restrict__ dinv,
                                                    float* __restrict__ Sf) {
    int e = blockIdx.x * 512 + threadIdx.x;
    if (e < NE) {
        int r = erow[e], c = ecol[e];
        atomicAdd(&Sf[c * 512 + r], dinv[r] * dinv[c]);
    }
}

// ---------------------------------------------------------------------------
// K3: Sb = bf16(Sf); E1T[dim][node] = (emb @ W1)^T in bf16 (layer-1 GEMM is
// batch-independent: hW1 = x * (emb@W1)).
// ---------------------------------------------------------------------------
__global__ __launch_bounds__(256) void prep_sb_e1t(const float* __restrict__ Sf,
                                                   const float* __restrict__ emb,
                                                   const float* __restrict__ W1,
                                                   short* __restrict__ Sb,
                                                   short* __restrict__ E1T) {
    int g = blockIdx.x * 256 + threadIdx.x;
    if (g < NUM * NUM) {
        Sb[g] = f2bf(Sf[g]);
    } else {
        int j = g - NUM * NUM;            // < 32768
        int node = j >> 6, dim = j & 63;
        float acc = 0.0f;
        #pragma unroll
        for (int d = 0; d < HD; ++d) acc += emb[node * HD + d] * W1[d * HD + dim];
        E1T[dim * NUM + node] = f2bf(acc);
    }
}

// ---------------------------------------------------------------------------
// Fused main kernel: one block (512 thr, 8 waves) per batch element.
// All GEMMs dense via mfma_f32_16x16x32_bf16, computed TRANSPOSED:
//   aggᵀ = Hᵀ(LDS, [dim][node]) · Sᵀ(global Sb rows, k-contiguous)
// so both MFMA operand reads are contiguous 16B.
// ---------------------------------------------------------------------------
__global__ __launch_bounds__(512) void gcn_fused(
    const float* __restrict__ x, const float* __restrict__ W2,
    const float* __restrict__ b1, const float* __restrict__ b2,
    const float* __restrict__ W3, const float* __restrict__ b3,
    const short* __restrict__ Sb, const short* __restrict__ E1T,
    float* __restrict__ out)
{
    __shared__ short TA[HD * TSTR];    // [dim][node]: T0 = (x*E1)^T, later T2
    __shared__ short TB[NUM * NSTR];   // [node][dim]: T1 = h1, later T3 = h2
    __shared__ short Wl[HD * WSTR];    // W2^T: Wl[m][k] = W2[k][m]
    __shared__ float xs[NUM];
    __shared__ float tvec[NUM];
    __shared__ float slog[NUM];
    __shared__ float sb1[HD], sb2[HD], sW3[HD];
    __shared__ float sred[2];

    const int t     = threadIdx.x;
    const int b     = blockIdx.x;
    const int lane  = t & 63;
    const int wave  = t >> 6;
    const int q     = lane >> 4;
    const int l15   = lane & 15;
    const int nbase = wave * 64;       // this wave's 64-node output strip

    // ---- stage 0: x, biases, W3, W2^T
    xs[t] = x[b * NUM + t];
    if (t < HD) { sb1[t] = b1[t]; sb2[t] = b2[t]; sW3[t] = W3[t]; }
    for (int i = t; i < HD * HD; i += 512) {
        int k = i >> 6, m = i & 63;
        Wl[m * WSTR + k] = f2bf(W2[i]);
    }
    __syncthreads();

    // ---- T0[dim][node] = x[node] * E1T[dim][node]  (vec8)
    for (int i = t; i < HD * NUM / 8; i += 512) {
        int dim = i >> 6, n8 = (i & 63) << 3;
        short8 e = *(const short8*)&E1T[dim * NUM + n8];
        short8 o;
        #pragma unroll
        for (int j = 0; j < 8; ++j) o[j] = f2bf(xs[n8 + j] * bf2f(e[j]));
        *(short8*)&TA[dim * TSTR + n8] = o;
    }
    __syncthreads();

    // ---- dense aggregation: TB[node][dim] = relu(bias + (S @ TA^T))^  (per-wave
    //      64-node strip; M=64 dims, N=64 nodes, K=512; A=TA LDS, B=Sb global)
    auto agg = [&](const float* __restrict__ bias) {
        f32x4 acc[4][4];
        #pragma unroll
        for (int mt = 0; mt < 4; ++mt)
            #pragma unroll
            for (int nt = 0; nt < 4; ++nt) acc[mt][nt] = (f32x4){0.f, 0.f, 0.f, 0.f};

        short8 bcur[4];
        #pragma unroll
        for (int nt = 0; nt < 4; ++nt)
            bcur[nt] = *(const short8*)&Sb[(nbase + nt * 16 + l15) * NUM + q * 8];

        #pragma unroll
        for (int ks = 0; ks < 16; ++ks) {
            short8 bnext[4];
            if (ks < 15) {
                #pragma unroll
                for (int nt = 0; nt < 4; ++nt)
                    bnext[nt] = *(const short8*)&Sb[(nbase + nt * 16 + l15) * NUM
                                                    + (ks + 1) * 32 + q * 8];
            }
            short8 af[4];
            #pragma unroll
            for (int mt = 0; mt < 4; ++mt)
                af[mt] = *(const short8*)&TA[(mt * 16 + l15) * TSTR + ks * 32 + q * 8];
            #pragma unroll
            for (int mt = 0; mt < 4; ++mt)
                #pragma unroll
                for (int nt = 0; nt < 4; ++nt)
                    acc[mt][nt] = __builtin_amdgcn_mfma_f32_16x16x32_bf16(
                        af[mt], bcur[nt], acc[mt][nt], 0, 0, 0);
            #pragma unroll
            for (int nt = 0; nt < 4; ++nt) bcur[nt] = bnext[nt];
        }
        // epilogue: C'[m=dim][n=node]; regs i -> m = mt*16+q*4+i (contiguous!)
        // pack 4 bf16 -> one ds_write_b64 into [node][dim] layout
        #pragma unroll
        for (int mt = 0; mt < 4; ++mt)
            #pragma unroll
            for (int nt = 0; nt < 4; ++nt) {
                short4v o;
                #pragma unroll
                for (int i = 0; i < 4; ++i) {
                    int m = mt * 16 + q * 4 + i;
                    o[i] = f2bf(fmaxf(acc[mt][nt][i] + bias[m], 0.0f));
                }
                *(short4v*)&TB[(nbase + nt * 16 + l15) * NSTR + mt * 16 + q * 4] = o;
            }
    };

    // ---- layer 1 aggregate: TA -> TB (h1, [node][dim])
    agg(sb1);
    __syncthreads();

    // ---- hW2^T = W2^T @ h1^T: M=64, N=64/wave, K=64 -> TA[dim][node]
    {
        f32x4 acc[4][4];
        #pragma unroll
        for (int mt = 0; mt < 4; ++mt)
            #pragma unroll
            for (int nt = 0; nt < 4; ++nt) acc[mt][nt] = (f32x4){0.f, 0.f, 0.f, 0.f};
        #pragma unroll
        for (int ks = 0; ks < 2; ++ks) {
            short8 af[4], bf_[4];
            #pragma unroll
            for (int mt = 0; mt < 4; ++mt)
                af[mt] = *(const short8*)&Wl[(mt * 16 + l15) * WSTR + ks * 32 + q * 8];
            #pragma unroll
            for (int nt = 0; nt < 4; ++nt)
                bf_[nt] = *(const short8*)&TB[(nbase + nt * 16 + l15) * NSTR + ks * 32 + q * 8];
            #pragma unroll
            for (int mt = 0; mt < 4; ++mt)
                #pragma unroll
                for (int nt = 0; nt < 4; ++nt)
                    acc[mt][nt] = __builtin_amdgcn_mfma_f32_16x16x32_bf16(
                        af[mt], bf_[nt], acc[mt][nt], 0, 0, 0);
        }
        #pragma unroll
        for (int mt = 0; mt < 4; ++mt)
            #pragma unroll
            for (int nt = 0; nt < 4; ++nt)
                #pragma unroll
                for (int i = 0; i < 4; ++i)
                    TA[(mt * 16 + q * 4 + i) * TSTR + nbase + nt * 16 + l15] =
                        f2bf(acc[mt][nt][i]);
    }
    __syncthreads();

    // ---- layer 2 aggregate: TA -> TB (h2, [node][dim])
    agg(sb2);
    __syncthreads();

    // ---- t[node] = h2[node,:] . W3   (per-thread contiguous b128 reads)
    {
        float a = 0.0f;
        #pragma unroll
        for (int k8 = 0; k8 < 8; ++k8) {
            short8 h = *(const short8*)&TB[t * NSTR + k8 * 8];
            #pragma unroll
            for (int j = 0; j < 8; ++j) a += bf2f(h[j]) * sW3[k8 * 8 + j];
        }
        tvec[t] = a;
    }
    __syncthreads();

    // ---- logits = S @ t + b3: wave-per-64-rows, lane-split K, butterfly reduce
    {
        float tj[8];
        #pragma unroll
        for (int j = 0; j < 8; ++j) tj[j] = tvec[lane * 8 + j];
        float bb3 = b3[0];
        for (int i = 0; i < 16; ++i) {      // 4 rows per iter: independent bfly chains
            float a[4];
            #pragma unroll
            for (int rr = 0; rr < 4; ++rr) {
                int r = nbase + i * 4 + rr;
                short8 s = *(const short8*)&Sb[r * NUM + lane * 8];
                float acc = 0.0f;
                #pragma unroll
                for (int j = 0; j < 8; ++j) acc += bf2f(s[j]) * tj[j];
                a[rr] = acc;
            }
            #pragma unroll
            for (int ofs = 32; ofs >= 1; ofs >>= 1) {
                #pragma unroll
                for (int rr = 0; rr < 4; ++rr) a[rr] += __shfl_xor(a[rr], ofs, 64);
            }
            if (lane == 0) {
                int r = nbase + i * 4;
                slog[r]     = a[0] + bb3;
                slog[r + 1] = a[1] + bb3;
                slog[r + 2] = a[2] + bb3;
                slog[r + 3] = a[3] + bb3;
            }
        }
    }
    __syncthreads();

    // ---- softmax stats over [0, MAIN) (wave 0, 16-lane butterfly)
    if (wave == 0) {
        float v = (lane < MAIN) ? slog[lane] : -1e30f;
        float m = v;
        #pragma unroll
        for (int ofs = 8; ofs >= 1; ofs >>= 1) m = fmaxf(m, __shfl_xor(m, ofs, 64));
        float e = (lane < MAIN) ? __expf(v - m) : 0.0f;
        float s = e;
        #pragma unroll
        for (int ofs = 8; ofs >= 1; ofs >>= 1) s += __shfl_xor(s, ofs, 64);
        if (lane == 0) { sred[0] = m; sred[1] = s; }
    }
    __syncthreads();

    {
        float l = slog[t];
        float o = (t < MAIN) ? __expf(l - sred[0]) / sred[1]
                             : 1.0f / (1.0f + __expf(-l));
        out[b * NUM + t] = o;
    }
}

// ---------------------------------------------------------------------------
extern "C" void kernel_launch(void* const* d_in, const int* in_sizes, int n_in,
                              void* d_out, int out_size, void* d_ws, size_t ws_size,
                              hipStream_t stream) {
    const float* x    = (const float*)d_in[0];
    const float* emb  = (const float*)d_in[1];
    const float* W1   = (const float*)d_in[2];
    const float* b1   = (const float*)d_in[3];
    const float* W2   = (const float*)d_in[4];
    const float* b2   = (const float*)d_in[5];
    const float* W3   = (const float*)d_in[6];
    const float* b3   = (const float*)d_in[7];
    const int*   erow = (const int*)d_in[8];
    const int*   ecol = (const int*)d_in[9];

    char* ws = (char*)d_ws;
    float* Sf   = (float*)ws;                     // 512*512*4 = 1 MB
    short* Sb   = (short*)(ws + 1048576);         // 512*512*2 = 512 KB
    short* E1T  = (short*)(ws + 1572864);         // 64*512*2  = 64 KB
    float* dinv = (float*)(ws + 1638400);         // 2 KB

    prep_zero_dinv<<<513, 512, 0, stream>>>(ecol, Sf, dinv);
    prep_scatter<<<8, 512, 0, stream>>>(erow, ecol, dinv, Sf);
    prep_sb_e1t<<<1152, 256, 0, stream>>>(Sf, emb, W1, Sb, E1T);
    gcn_fused<<<NB, 512, 0, stream>>>(x, W2, b1, b2, W3, b3, Sb, E1T,
                                      (float*)d_out);
}

// Round 3
// 259.823 us; speedup vs baseline: 1.3517x; 1.0367x over previous
//
#include <hip/hip_runtime.h>
#include <stdint.h>

#define NB    1024   // batch
#define NUM   512    // nodes
#define HD    64     // hidden dim
#define NE    4096   // edges
#define MAIN  10     // softmax segment
#define TSTR  520    // [dim][node] LDS stride (shorts)
#define NSTR  72     // [node][dim] LDS stride (shorts)
#define WSTR  72     // W2^T LDS stride

typedef __attribute__((ext_vector_type(8))) short short8;
typedef __attribute__((ext_vector_type(4))) short short4v;
typedef __attribute__((ext_vector_type(4))) float f32x4;

__device__ __forceinline__ short f2bf(float f) {
    uint32_t u = __float_as_uint(f);
    u += 0x7fffu + ((u >> 16) & 1u);   // RNE
    return (short)(u >> 16);
}
__device__ __forceinline__ float bf2f(short s) {
    return __uint_as_float(((uint32_t)(uint16_t)s) << 16);
}

// ---------------------------------------------------------------------------
// K1: blocks 0..511 zero Sf; block 512 computes dinv.
// ---------------------------------------------------------------------------
__global__ __launch_bounds__(512) void prep_zero_dinv(const int* __restrict__ ecol,
                                                      float* __restrict__ Sf,
                                                      float* __restrict__ dinv) {
    const int b = blockIdx.x, t = threadIdx.x;
    if (b < 512) {
        Sf[b * 512 + t] = 0.0f;
    } else {
        __shared__ int sdeg[NUM];
        sdeg[t] = 0;
        __syncthreads();
        for (int e = t; e < NE; e += 512) atomicAdd(&sdeg[ecol[e]], 1);
        __syncthreads();
        int d = sdeg[t];
        dinv[t] = d > 0 ? rsqrtf((float)d) : 0.0f;
    }
}

// ---------------------------------------------------------------------------
// K2: scatter edge norms into dense Sf[c][r].
// ---------------------------------------------------------------------------
__global__ __launch_bounds__(512) void prep_scatter(const int* __restrict__ erow,
                                                    const int* __restrict__ ecol,
                                                    const float* __restrict__ dinv,
                                                    float* __restrict__ Sf) {
    int e = blockIdx.x * 512 + threadIdx.x;
    if (e < NE) {
        int r = erow[e], c = ecol[e];
        atomicAdd(&Sf[c * 512 + r], dinv[r] * dinv[c]);
    }
}

// ---------------------------------------------------------------------------
// K3: Sb = bf16(Sf); E1T[dim][node] = (emb @ W1)^T bf16.
// ---------------------------------------------------------------------------
__global__ __launch_bounds__(256) void prep_sb_e1t(const float* __restrict__ Sf,
                                                   const float* __restrict__ emb,
                                                   const float* __restrict__ W1,
                                                   short* __restrict__ Sb,
                                                   short* __restrict__ E1T) {
    int g = blockIdx.x * 256 + threadIdx.x;
    if (g < NUM * NUM) {
        Sb[g] = f2bf(Sf[g]);
    } else {
        int j = g - NUM * NUM;
        int node = j >> 6, dim = j & 63;
        float acc = 0.0f;
        #pragma unroll
        for (int d = 0; d < HD; ++d) acc += emb[node * HD + d] * W1[d * HD + dim];
        E1T[dim * NUM + node] = f2bf(acc);
    }
}

// ---------------------------------------------------------------------------
// Fused main kernel: ONE BLOCK = 1024 threads (16 waves) per batch element.
// 16 waves/CU = 4 waves/SIMD (vs 2 at 512 thr) — doubles latency hiding on the
// L2-latency-bound Sb loads. Each wave owns a 32-node output strip.
// ---------------------------------------------------------------------------
__global__ __launch_bounds__(1024) void gcn_fused(
    const float* __restrict__ x, const float* __restrict__ W2,
    const float* __restrict__ b1, const float* __restrict__ b2,
    const float* __restrict__ W3, const float* __restrict__ b3,
    const short* __restrict__ Sb, const short* __restrict__ E1T,
    float* __restrict__ out)
{
    __shared__ short TA[HD * TSTR];    // [dim][node]: T0 = (x*E1)^T, later hW2^T
    __shared__ short TB[NUM * NSTR];   // [node][dim]: h1, later h2
    __shared__ short Wl[HD * WSTR];    // W2^T
    __shared__ float xs[NUM];
    __shared__ float tvec[NUM];
    __shared__ float slog[NUM];
    __shared__ float sb1[HD], sb2[HD], sW3[HD];
    __shared__ float sred[2];

    const int t     = threadIdx.x;
    const int b     = blockIdx.x;
    const int lane  = t & 63;
    const int wave  = t >> 6;          // 0..15
    const int q     = lane >> 4;
    const int l15   = lane & 15;
    const int nbase = wave * 32;       // this wave's 32-node output strip

    // ---- stage 0
    if (t < NUM) xs[t] = x[b * NUM + t];
    if (t < HD) { sb1[t] = b1[t]; sb2[t] = b2[t]; sW3[t] = W3[t]; }
    for (int i = t; i < HD * HD; i += 1024) {
        int k = i >> 6, m = i & 63;
        Wl[m * WSTR + k] = f2bf(W2[i]);
    }
    __syncthreads();

    // ---- T0[dim][node] = x[node] * E1T[dim][node]
    for (int i = t; i < HD * NUM / 8; i += 1024) {
        int dim = i >> 6, n8 = (i & 63) << 3;
        short8 e = *(const short8*)&E1T[dim * NUM + n8];
        short8 o;
        #pragma unroll
        for (int j = 0; j < 8; ++j) o[j] = f2bf(xs[n8 + j] * bf2f(e[j]));
        *(short8*)&TA[dim * TSTR + n8] = o;
    }
    __syncthreads();

    // ---- dense aggregation (per-wave 32-node strip):
    //      TB[node][dim] = relu(bias + S @ H), H^T in TA. M=64 dims, N=32, K=512.
    //      2-deep prefetch of Sb B-fragments to cover L2 latency.
    auto agg = [&](const float* __restrict__ bias) {
        f32x4 acc[4][2];
        #pragma unroll
        for (int mt = 0; mt < 4; ++mt)
            #pragma unroll
            for (int nt = 0; nt < 2; ++nt) acc[mt][nt] = (f32x4){0.f, 0.f, 0.f, 0.f};

        short8 bq[2][2];   // [pipe slot][nt]
        #pragma unroll
        for (int p = 0; p < 2; ++p)
            #pragma unroll
            for (int nt = 0; nt < 2; ++nt)
                bq[p][nt] = *(const short8*)&Sb[(nbase + nt * 16 + l15) * NUM
                                                + p * 32 + q * 8];
        #pragma unroll
        for (int ks = 0; ks < 16; ++ks) {
            short8 bcur[2] = { bq[ks & 1][0], bq[ks & 1][1] };
            if (ks + 2 < 16) {
                #pragma unroll
                for (int nt = 0; nt < 2; ++nt)
                    bq[ks & 1][nt] = *(const short8*)&Sb[(nbase + nt * 16 + l15) * NUM
                                                         + (ks + 2) * 32 + q * 8];
            }
            short8 af[4];
            #pragma unroll
            for (int mt = 0; mt < 4; ++mt)
                af[mt] = *(const short8*)&TA[(mt * 16 + l15) * TSTR + ks * 32 + q * 8];
            #pragma unroll
            for (int mt = 0; mt < 4; ++mt)
                #pragma unroll
                for (int nt = 0; nt < 2; ++nt)
                    acc[mt][nt] = __builtin_amdgcn_mfma_f32_16x16x32_bf16(
                        af[mt], bcur[nt], acc[mt][nt], 0, 0, 0);
        }
        // epilogue: C[m=dim][n=node]; pack 4 bf16 -> ds_write_b64 into [node][dim]
        #pragma unroll
        for (int mt = 0; mt < 4; ++mt)
            #pragma unroll
            for (int nt = 0; nt < 2; ++nt) {
                short4v o;
                #pragma unroll
                for (int i = 0; i < 4; ++i) {
                    int m = mt * 16 + q * 4 + i;
                    o[i] = f2bf(fmaxf(acc[mt][nt][i] + bias[m], 0.0f));
                }
                *(short4v*)&TB[(nbase + nt * 16 + l15) * NSTR + mt * 16 + q * 4] = o;
            }
    };

    // ---- layer 1 aggregate: TA -> TB (h1)
    agg(sb1);
    __syncthreads();

    // ---- hW2^T = W2^T @ h1^T: M=64, N=32/wave, K=64 -> TA[dim][node]
    {
        f32x4 acc[4][2];
        #pragma unroll
        for (int mt = 0; mt < 4; ++mt)
            #pragma unroll
            for (int nt = 0; nt < 2; ++nt) acc[mt][nt] = (f32x4){0.f, 0.f, 0.f, 0.f};
        #pragma unroll
        for (int ks = 0; ks < 2; ++ks) {
            short8 af[4], bf_[2];
            #pragma unroll
            for (int mt = 0; mt < 4; ++mt)
                af[mt] = *(const short8*)&Wl[(mt * 16 + l15) * WSTR + ks * 32 + q * 8];
            #pragma unroll
            for (int nt = 0; nt < 2; ++nt)
                bf_[nt] = *(const short8*)&TB[(nbase + nt * 16 + l15) * NSTR + ks * 32 + q * 8];
            #pragma unroll
            for (int mt = 0; mt < 4; ++mt)
                #pragma unroll
                for (int nt = 0; nt < 2; ++nt)
                    acc[mt][nt] = __builtin_amdgcn_mfma_f32_16x16x32_bf16(
                        af[mt], bf_[nt], acc[mt][nt], 0, 0, 0);
        }
        #pragma unroll
        for (int mt = 0; mt < 4; ++mt)
            #pragma unroll
            for (int nt = 0; nt < 2; ++nt)
                #pragma unroll
                for (int i = 0; i < 4; ++i)
                    TA[(mt * 16 + q * 4 + i) * TSTR + nbase + nt * 16 + l15] =
                        f2bf(acc[mt][nt][i]);
    }
    __syncthreads();

    // ---- layer 2 aggregate: TA -> TB (h2)
    agg(sb2);
    __syncthreads();

    // ---- t[node] = h2[node,:] . W3
    if (t < NUM) {
        float a = 0.0f;
        #pragma unroll
        for (int k8 = 0; k8 < 8; ++k8) {
            short8 h = *(const short8*)&TB[t * NSTR + k8 * 8];
            #pragma unroll
            for (int j = 0; j < 8; ++j) a += bf2f(h[j]) * sW3[k8 * 8 + j];
        }
        tvec[t] = a;
    }
    __syncthreads();

    // ---- logits = S @ t + b3: per-wave 32 rows, lane-split K, 4-chain butterfly
    {
        float tj[8];
        #pragma unroll
        for (int j = 0; j < 8; ++j) tj[j] = tvec[lane * 8 + j];
        float bb3 = b3[0];
        for (int i = 0; i < 8; ++i) {
            float a[4];
            #pragma unroll
            for (int rr = 0; rr < 4; ++rr) {
                int r = nbase + i * 4 + rr;
                short8 s = *(const short8*)&Sb[r * NUM + lane * 8];
                float acc = 0.0f;
                #pragma unroll
                for (int j = 0; j < 8; ++j) acc += bf2f(s[j]) * tj[j];
                a[rr] = acc;
            }
            #pragma unroll
            for (int ofs = 32; ofs >= 1; ofs >>= 1) {
                #pragma unroll
                for (int rr = 0; rr < 4; ++rr) a[rr] += __shfl_xor(a[rr], ofs, 64);
            }
            if (lane == 0) {
                int r = nbase + i * 4;
                slog[r]     = a[0] + bb3;
                slog[r + 1] = a[1] + bb3;
                slog[r + 2] = a[2] + bb3;
                slog[r + 3] = a[3] + bb3;
            }
        }
    }
    __syncthreads();

    // ---- softmax stats over [0, MAIN)
    if (wave == 0) {
        float v = (lane < MAIN) ? slog[lane] : -1e30f;
        float m = v;
        #pragma unroll
        for (int ofs = 8; ofs >= 1; ofs >>= 1) m = fmaxf(m, __shfl_xor(m, ofs, 64));
        float e = (lane < MAIN) ? __expf(v - m) : 0.0f;
        float s = e;
        #pragma unroll
        for (int ofs = 8; ofs >= 1; ofs >>= 1) s += __shfl_xor(s, ofs, 64);
        if (lane == 0) { sred[0] = m; sred[1] = s; }
    }
    __syncthreads();

    if (t < NUM) {
        float l = slog[t];
        float o = (t < MAIN) ? __expf(l - sred[0]) / sred[1]
                             : 1.0f / (1.0f + __expf(-l));
        out[b * NUM + t] = o;
    }
}

// ---------------------------------------------------------------------------
extern "C" void kernel_launch(void* const* d_in, const int* in_sizes, int n_in,
                              void* d_out, int out_size, void* d_ws, size_t ws_size,
                              hipStream_t stream) {
    const float* x    = (const float*)d_in[0];
    const float* emb  = (const float*)d_in[1];
    const float* W1   = (const float*)d_in[2];
    const float* b1   = (const float*)d_in[3];
    const float* W2   = (const float*)d_in[4];
    const float* b2   = (const float*)d_in[5];
    const float* W3   = (const float*)d_in[6];
    const float* b3   = (const float*)d_in[7];
    const int*   erow = (const int*)d_in[8];
    const int*   ecol = (const int*)d_in[9];

    char* ws = (char*)d_ws;
    float* Sf   = (float*)ws;                     // 1 MB
    short* Sb   = (short*)(ws + 1048576);         // 512 KB
    short* E1T  = (short*)(ws + 1572864);         // 64 KB
    float* dinv = (float*)(ws + 1638400);         // 2 KB

    prep_zero_dinv<<<513, 512, 0, stream>>>(ecol, Sf, dinv);
    prep_scatter<<<8, 512, 0, stream>>>(erow, ecol, dinv, Sf);
    prep_sb_e1t<<<1152, 256, 0, stream>>>(Sf, emb, W1, Sb, E1T);
    gcn_fused<<<NB, 1024, 0, stream>>>(x, W2, b1, b2, W3, b3, Sb, E1T,
                                       (float*)d_out);
}

// Round 4
// 231.150 us; speedup vs baseline: 1.5194x; 1.1240x over previous
//
#include <hip/hip_runtime.h>
#include <stdint.h>

#define NB    1024   // batch
#define NUM   512    // nodes
#define HD    64     // hidden dim
#define NE    4096   // edges
#define MAIN  10     // softmax segment

typedef __attribute__((ext_vector_type(8))) short short8;
typedef __attribute__((ext_vector_type(4))) short short4v;
typedef __attribute__((ext_vector_type(4))) float f32x4;

__device__ __forceinline__ short f2bf(float f) {
    uint32_t u = __float_as_uint(f);
    u += 0x7fffu + ((u >> 16) & 1u);   // RNE
    return (short)(u >> 16);
}
__device__ __forceinline__ float bf2f(short s) {
    return __uint_as_float(((uint32_t)(uint16_t)s) << 16);
}

// ---------------------------------------------------------------------------
// K1: blocks 0..511 zero Sf; block 512 computes dinv.
// ---------------------------------------------------------------------------
__global__ __launch_bounds__(512) void prep_zero_dinv(const int* __restrict__ ecol,
                                                      float* __restrict__ Sf,
                                                      float* __restrict__ dinv) {
    const int b = blockIdx.x, t = threadIdx.x;
    if (b < 512) {
        Sf[b * 512 + t] = 0.0f;
    } else {
        __shared__ int sdeg[NUM];
        sdeg[t] = 0;
        __syncthreads();
        for (int e = t; e < NE; e += 512) atomicAdd(&sdeg[ecol[e]], 1);
        __syncthreads();
        int d = sdeg[t];
        dinv[t] = d > 0 ? rsqrtf((float)d) : 0.0f;
    }
}

// ---------------------------------------------------------------------------
// K2: scatter edge norms into dense Sf[c][r].
// ---------------------------------------------------------------------------
__global__ __launch_bounds__(512) void prep_scatter(const int* __restrict__ erow,
                                                    const int* __restrict__ ecol,
                                                    const float* __restrict__ dinv,
                                                    float* __restrict__ Sf) {
    int e = blockIdx.x * 512 + threadIdx.x;
    if (e < NE) {
        int r = erow[e], c = ecol[e];
        atomicAdd(&Sf[c * 512 + r], dinv[r] * dinv[c]);
    }
}

// ---------------------------------------------------------------------------
// K3: Sb = bf16(Sf); E1T[d][r] = (emb@W1)^T bf16; W2T[dout][d] = W2^T bf16.
// ---------------------------------------------------------------------------
__global__ __launch_bounds__(256) void prep_cast(const float* __restrict__ Sf,
                                                 const float* __restrict__ emb,
                                                 const float* __restrict__ W1,
                                                 const float* __restrict__ W2,
                                                 short* __restrict__ Sb,
                                                 short* __restrict__ E1T,
                                                 short* __restrict__ W2T) {
    int g = blockIdx.x * 256 + threadIdx.x;
    if (g < NUM * NUM) {
        Sb[g] = f2bf(Sf[g]);
    } else if (g < NUM * NUM + HD * NUM) {
        int j = g - NUM * NUM;
        int d = j >> 9, r = j & 511;
        float acc = 0.0f;
        #pragma unroll
        for (int k = 0; k < HD; ++k) acc += emb[r * HD + k] * W1[k * HD + d];
        E1T[j] = f2bf(acc);
    } else if (g < NUM * NUM + HD * NUM + HD * HD) {
        int j = g - NUM * NUM - HD * NUM;
        int dout = j >> 6, d = j & 63;
        W2T[j] = f2bf(W2[d * HD + dout]);
    }
}

// ---------------------------------------------------------------------------
// agg1: h1T[n][c] = relu( (S @ B1)[c,n] + b1[d(n)] ),  B1[r,n] = x[b(n),r]*E1[r,d(n)]
// M=512 (c, grid.x*128), N=cols (grid.y*128, 2 batches each), K=512 (r).
// 128x128 tile, BK=64, 8 waves (wave grid 2M x 4N), 16x16x32 bf16 MFMA.
// ---------------------------------------------------------------------------
__global__ __launch_bounds__(512, 4) void agg1_gemm(
    const short* __restrict__ Sb, const short* __restrict__ E1T,
    const float* __restrict__ x, const float* __restrict__ b1,
    short* __restrict__ h1T, int b0)
{
    __shared__ short As[128 * 72];   // S tile  [c][r]
    __shared__ short Bt[128 * 72];   // B1 tile [n][r]
    __shared__ float sb1[HD];

    const int t = threadIdx.x;
    const int ctile = blockIdx.x, ntile = blockIdx.y;
    const int lane = t & 63, wave = t >> 6;
    const int q = lane >> 4, l15 = lane & 15;
    const int wm = wave >> 2, wn = wave & 3;
    const int bb = b0 + ntile * 2;       // first of this tile's 2 batches

    if (t < HD) sb1[t] = b1[t];

    f32x4 acc[4][2];
    #pragma unroll
    for (int mt = 0; mt < 4; ++mt)
        #pragma unroll
        for (int nt = 0; nt < 2; ++nt) acc[mt][nt] = (f32x4){0.f, 0.f, 0.f, 0.f};

    for (int k0 = 0; k0 < NUM; k0 += 64) {
        __syncthreads();
        // stage A: S[ctile*128 + row][k0 + 0..63]
        #pragma unroll
        for (int p = 0; p < 2; ++p) {
            int idx = t + p * 512;
            int row = idx >> 3, seg = (idx & 7) * 8;
            short8 v = *(const short8*)&Sb[(ctile * 128 + row) * NUM + k0 + seg];
            *(short8*)&As[row * 72 + seg] = v;
        }
        // build B: Bt[n][r] = x[bb + n/64][k0+r] * E1T[n%64][k0+r]
        #pragma unroll
        for (int p = 0; p < 2; ++p) {
            int idx = t + p * 512;
            int n = idx >> 3, r8 = (idx & 7) * 8;
            int bloc = n >> 6, d = n & 63;
            short8 e = *(const short8*)&E1T[d * NUM + k0 + r8];
            const float* xp = &x[(bb + bloc) * NUM + k0 + r8];
            f32x4 x0 = *(const f32x4*)xp;
            f32x4 x1 = *(const f32x4*)(xp + 4);
            short8 o;
            o[0] = f2bf(x0[0] * bf2f(e[0])); o[1] = f2bf(x0[1] * bf2f(e[1]));
            o[2] = f2bf(x0[2] * bf2f(e[2])); o[3] = f2bf(x0[3] * bf2f(e[3]));
            o[4] = f2bf(x1[0] * bf2f(e[4])); o[5] = f2bf(x1[1] * bf2f(e[5]));
            o[6] = f2bf(x1[2] * bf2f(e[6])); o[7] = f2bf(x1[3] * bf2f(e[7]));
            *(short8*)&Bt[n * 72 + r8] = o;
        }
        __syncthreads();
        #pragma unroll
        for (int ks = 0; ks < 2; ++ks) {
            short8 af[4], bf_[2];
            #pragma unroll
            for (int mt = 0; mt < 4; ++mt)
                af[mt] = *(const short8*)&As[(wm * 64 + mt * 16 + l15) * 72 + ks * 32 + q * 8];
            #pragma unroll
            for (int nt = 0; nt < 2; ++nt)
                bf_[nt] = *(const short8*)&Bt[(wn * 32 + nt * 16 + l15) * 72 + ks * 32 + q * 8];
            #pragma unroll
            for (int mt = 0; mt < 4; ++mt)
                #pragma unroll
                for (int nt = 0; nt < 2; ++nt)
                    acc[mt][nt] = __builtin_amdgcn_mfma_f32_16x16x32_bf16(
                        af[mt], bf_[nt], acc[mt][nt], 0, 0, 0);
        }
    }
    // epilogue: relu(+b1) -> h1T[n][c] bf16 (short4 packs over i)
    #pragma unroll
    for (int nt = 0; nt < 2; ++nt) {
        int ncol = wn * 32 + nt * 16 + l15;
        float bv = sb1[ncol & 63];
        size_t nl = (size_t)(ntile * 128 + ncol);
        #pragma unroll
        for (int mt = 0; mt < 4; ++mt) {
            short4v o;
            #pragma unroll
            for (int i = 0; i < 4; ++i)
                o[i] = f2bf(fmaxf(acc[mt][nt][i] + bv, 0.0f));
            int c = ctile * 128 + wm * 64 + mt * 16 + q * 4;
            *(short4v*)&h1T[nl * NUM + c] = o;
        }
    }
}

// ---------------------------------------------------------------------------
// agg2: g2 = S @ h1 (same GEMM); epilogue: t = relu(g2@W2 + b2) @ W3,
// via in-LDS T round-trip + second MFMA pass. Writes t[b][c] bf16.
// ---------------------------------------------------------------------------
__global__ __launch_bounds__(512, 4) void agg2_gemm(
    const short* __restrict__ Sb, const short* __restrict__ h1T,
    const short* __restrict__ W2T, const float* __restrict__ b2,
    const float* __restrict__ W3, short* __restrict__ tglob, int b0)
{
    __shared__ short sm[18432 + 64 * 72];   // As(9216) + Bt(9216) overlapped by T(17408); W2s after
    __shared__ float sb2[HD], sw3[HD];
    short* As  = sm;
    short* Bt  = sm + 9216;
    short* T   = sm;            // reuses As+Bt region after K-loop
    short* W2s = sm + 18432;

    const int t = threadIdx.x;
    const int ctile = blockIdx.x, ntile = blockIdx.y;
    const int lane = t & 63, wave = t >> 6;
    const int q = lane >> 4, l15 = lane & 15;
    const int wm = wave >> 2, wn = wave & 3;

    if (t < HD) { sb2[t] = b2[t]; sw3[t] = W3[t]; }
    // stage W2s[dout][d] (stride 72)
    {
        int row = t >> 3, seg = (t & 7) * 8;
        *(short8*)&W2s[row * 72 + seg] = *(const short8*)&W2T[row * HD + seg];
    }

    f32x4 acc[4][2];
    #pragma unroll
    for (int mt = 0; mt < 4; ++mt)
        #pragma unroll
        for (int nt = 0; nt < 2; ++nt) acc[mt][nt] = (f32x4){0.f, 0.f, 0.f, 0.f};

    for (int k0 = 0; k0 < NUM; k0 += 64) {
        __syncthreads();
        #pragma unroll
        for (int p = 0; p < 2; ++p) {
            int idx = t + p * 512;
            int row = idx >> 3, seg = (idx & 7) * 8;
            *(short8*)&As[row * 72 + seg] =
                *(const short8*)&Sb[(ctile * 128 + row) * NUM + k0 + seg];
            *(short8*)&Bt[row * 72 + seg] =
                *(const short8*)&h1T[(size_t)(ntile * 128 + row) * NUM + k0 + seg];
        }
        __syncthreads();
        #pragma unroll
        for (int ks = 0; ks < 2; ++ks) {
            short8 af[4], bf_[2];
            #pragma unroll
            for (int mt = 0; mt < 4; ++mt)
                af[mt] = *(const short8*)&As[(wm * 64 + mt * 16 + l15) * 72 + ks * 32 + q * 8];
            #pragma unroll
            for (int nt = 0; nt < 2; ++nt)
                bf_[nt] = *(const short8*)&Bt[(wn * 32 + nt * 16 + l15) * 72 + ks * 32 + q * 8];
            #pragma unroll
            for (int mt = 0; mt < 4; ++mt)
                #pragma unroll
                for (int nt = 0; nt < 2; ++nt)
                    acc[mt][nt] = __builtin_amdgcn_mfma_f32_16x16x32_bf16(
                        af[mt], bf_[nt], acc[mt][nt], 0, 0, 0);
        }
    }
    // ---- round-trip g2 tile into LDS T[c][n] (stride 136), bf16
    __syncthreads();
    #pragma unroll
    for (int mt = 0; mt < 4; ++mt)
        #pragma unroll
        for (int nt = 0; nt < 2; ++nt)
            #pragma unroll
            for (int i = 0; i < 4; ++i)
                T[(wm * 64 + mt * 16 + q * 4 + i) * 136 + wn * 32 + nt * 16 + l15] =
                    f2bf(acc[mt][nt][i]);
    __syncthreads();

    // ---- U = T_b @ W2 per batch-half; t = relu(U+b2)@W3. Wave: b = w&1, 32-c strip.
    {
        const int bsel = wave & 1;
        const int cs = (wave >> 1) * 32;
        f32x4 u[2][4];
        #pragma unroll
        for (int mt = 0; mt < 2; ++mt)
            #pragma unroll
            for (int nt = 0; nt < 4; ++nt) u[mt][nt] = (f32x4){0.f, 0.f, 0.f, 0.f};
        #pragma unroll
        for (int ks = 0; ks < 2; ++ks) {
            short8 af[2], bf_[4];
            #pragma unroll
            for (int mt = 0; mt < 2; ++mt)
                af[mt] = *(const short8*)&T[(cs + mt * 16 + l15) * 136 + bsel * 64 + ks * 32 + q * 8];
            #pragma unroll
            for (int nt = 0; nt < 4; ++nt)
                bf_[nt] = *(const short8*)&W2s[(nt * 16 + l15) * 72 + ks * 32 + q * 8];
            #pragma unroll
            for (int mt = 0; mt < 2; ++mt)
                #pragma unroll
                for (int nt = 0; nt < 4; ++nt)
                    u[mt][nt] = __builtin_amdgcn_mfma_f32_16x16x32_bf16(
                        af[mt], bf_[nt], u[mt][nt], 0, 0, 0);
        }
        // reduce over dout: p[mt][i] = sum_nt relu(u + b2[dout]) * W3[dout]
        float p[2][4];
        #pragma unroll
        for (int mt = 0; mt < 2; ++mt)
            #pragma unroll
            for (int i = 0; i < 4; ++i) {
                float a = 0.0f;
                #pragma unroll
                for (int nt = 0; nt < 4; ++nt) {
                    int dout = nt * 16 + l15;
                    a += fmaxf(u[mt][nt][i] + sb2[dout], 0.0f) * sw3[dout];
                }
                p[mt][i] = a;
            }
        #pragma unroll
        for (int ofs = 1; ofs <= 8; ofs <<= 1)
            #pragma unroll
            for (int mt = 0; mt < 2; ++mt)
                #pragma unroll
                for (int i = 0; i < 4; ++i)
                    p[mt][i] += __shfl_xor(p[mt][i], ofs, 64);
        if (l15 == 0) {
            size_t bg = (size_t)(b0 + ntile * 2 + bsel);
            #pragma unroll
            for (int mt = 0; mt < 2; ++mt) {
                short4v o;
                #pragma unroll
                for (int i = 0; i < 4; ++i) o[i] = f2bf(p[mt][i]);
                int c = ctile * 128 + cs + mt * 16 + q * 4;
                *(short4v*)&tglob[bg * NUM + c] = o;
            }
        }
    }
}

// ---------------------------------------------------------------------------
// final: logits = S @ t + b3 -> softmax rows [0,10) / sigmoid -> out[b][c] fp32
// M=512 (4 ctiles), N=1024 (8 btiles), K=512.
// ---------------------------------------------------------------------------
__global__ __launch_bounds__(512) void final_gemm(
    const short* __restrict__ Sb, const short* __restrict__ tglob,
    const float* __restrict__ b3p, float* __restrict__ out)
{
    __shared__ short As[128 * 72];
    __shared__ short Bt[128 * 72];

    const int t = threadIdx.x;
    const int ctile = blockIdx.x, btile = blockIdx.y;
    const int lane = t & 63, wave = t >> 6;
    const int q = lane >> 4, l15 = lane & 15;
    const int wm = wave >> 2, wn = wave & 3;

    f32x4 acc[4][2];
    #pragma unroll
    for (int mt = 0; mt < 4; ++mt)
        #pragma unroll
        for (int nt = 0; nt < 2; ++nt) acc[mt][nt] = (f32x4){0.f, 0.f, 0.f, 0.f};

    for (int k0 = 0; k0 < NUM; k0 += 64) {
        __syncthreads();
        #pragma unroll
        for (int p = 0; p < 2; ++p) {
            int idx = t + p * 512;
            int row = idx >> 3, seg = (idx & 7) * 8;
            *(short8*)&As[row * 72 + seg] =
                *(const short8*)&Sb[(ctile * 128 + row) * NUM + k0 + seg];
            *(short8*)&Bt[row * 72 + seg] =
                *(const short8*)&tglob[(size_t)(btile * 128 + row) * NUM + k0 + seg];
        }
        __syncthreads();
        #pragma unroll
        for (int ks = 0; ks < 2; ++ks) {
            short8 af[4], bf_[2];
            #pragma unroll
            for (int mt = 0; mt < 4; ++mt)
                af[mt] = *(const short8*)&As[(wm * 64 + mt * 16 + l15) * 72 + ks * 32 + q * 8];
            #pragma unroll
            for (int nt = 0; nt < 2; ++nt)
                bf_[nt] = *(const short8*)&Bt[(wn * 32 + nt * 16 + l15) * 72 + ks * 32 + q * 8];
            #pragma unroll
            for (int mt = 0; mt < 4; ++mt)
                #pragma unroll
                for (int nt = 0; nt < 2; ++nt)
                    acc[mt][nt] = __builtin_amdgcn_mfma_f32_16x16x32_bf16(
                        af[mt], bf_[nt], acc[mt][nt], 0, 0, 0);
        }
    }

    const float b3 = b3p[0];
    // softmax stats for rows 0..9 (only ctile==0, wm==0, mt==0 holds them)
    float mx[2] = {0.f, 0.f}, sm[2] = {0.f, 0.f};
    if (ctile == 0 && wm == 0) {
        #pragma unroll
        for (int nt = 0; nt < 2; ++nt) {
            float m = -1e30f;
            #pragma unroll
            for (int i = 0; i < 4; ++i) {
                int c = q * 4 + i;
                float l = acc[0][nt][i] + b3;
                m = (c < MAIN) ? fmaxf(m, l) : m;
            }
            m = fmaxf(m, __shfl_xor(m, 16, 64));
            m = fmaxf(m, __shfl_xor(m, 32, 64));
            float s = 0.0f;
            #pragma unroll
            for (int i = 0; i < 4; ++i) {
                int c = q * 4 + i;
                float l = acc[0][nt][i] + b3;
                s += (c < MAIN) ? __expf(l - m) : 0.0f;
            }
            s += __shfl_xor(s, 16, 64);
            s += __shfl_xor(s, 32, 64);
            mx[nt] = m; sm[nt] = s;
        }
    }
    #pragma unroll
    for (int nt = 0; nt < 2; ++nt) {
        size_t bcol = (size_t)(btile * 128 + wn * 32 + nt * 16 + l15);
        #pragma unroll
        for (int mt = 0; mt < 4; ++mt) {
            f32x4 o;
            #pragma unroll
            for (int i = 0; i < 4; ++i) {
                int c = ctile * 128 + wm * 64 + mt * 16 + q * 4 + i;
                float l = acc[mt][nt][i] + b3;
                o[i] = (c < MAIN) ? __expf(l - mx[nt]) / sm[nt]
                                  : 1.0f / (1.0f + __expf(-l));
            }
            *(f32x4*)&out[bcol * NUM + ctile * 128 + wm * 64 + mt * 16 + q * 4] = o;
        }
    }
}

// ---------------------------------------------------------------------------
extern "C" void kernel_launch(void* const* d_in, const int* in_sizes, int n_in,
                              void* d_out, int out_size, void* d_ws, size_t ws_size,
                              hipStream_t stream) {
    const float* x    = (const float*)d_in[0];
    const float* emb  = (const float*)d_in[1];
    const float* W1   = (const float*)d_in[2];
    const float* b1   = (const float*)d_in[3];
    const float* W2   = (const float*)d_in[4];
    const float* b2   = (const float*)d_in[5];
    const float* W3   = (const float*)d_in[6];
    const float* b3   = (const float*)d_in[7];
    const int*   erow = (const int*)d_in[8];
    const int*   ecol = (const int*)d_in[9];

    char* ws = (char*)d_ws;
    float* Sf   = (float*)ws;                     // [0, 1 MB)
    short* Sb   = (short*)(ws + 1048576);         // 512 KB
    short* E1T  = (short*)(ws + 1572864);         // 64 KB  [d][r]
    short* W2T  = (short*)(ws + 1638400);         // 8 KB   [dout][d]
    float* dinv = (float*)(ws + 1646592);         // 2 KB
    short* tg   = (short*)(ws + 1648640);         // 1 MB   t[b][r] bf16
    short* h1T  = (short*)(ws + 2697216);         // chunk: CB*64 rows x 512 bf16

    // pick largest batch chunk that fits the workspace
    int CB = 1024;
    while ((size_t)CB * 65536 + 2697216 > ws_size && CB > 16) CB >>= 1;
    int nchunks = NB / CB;

    prep_zero_dinv<<<513, 512, 0, stream>>>(ecol, Sf, dinv);
    prep_scatter<<<8, 512, 0, stream>>>(erow, ecol, dinv, Sf);
    prep_cast<<<1168, 256, 0, stream>>>(Sf, emb, W1, W2, Sb, E1T, W2T);

    for (int c = 0; c < nchunks; ++c) {
        int b0 = c * CB;
        agg1_gemm<<<dim3(4, CB / 2), 512, 0, stream>>>(Sb, E1T, x, b1, h1T, b0);
        agg2_gemm<<<dim3(4, CB / 2), 512, 0, stream>>>(Sb, h1T, W2T, b2, W3, tg, b0);
    }
    final_gemm<<<dim3(4, 8), 512, 0, stream>>>(Sb, tg, b3, (float*)d_out);
}

// Round 5
// 228.280 us; speedup vs baseline: 1.5385x; 1.0126x over previous
//
#include <hip/hip_runtime.h>
#include <stdint.h>

#define NB    1024   // batch
#define NUM   512    // nodes
#define HD    64     // hidden dim
#define NE    4096   // edges
#define MAIN  10     // softmax segment

typedef __attribute__((ext_vector_type(8))) short short8;
typedef __attribute__((ext_vector_type(4))) short short4v;
typedef __attribute__((ext_vector_type(4))) float f32x4;

__device__ __forceinline__ short f2bf(float f) {
    uint32_t u = __float_as_uint(f);
    u += 0x7fffu + ((u >> 16) & 1u);   // RNE
    return (short)(u >> 16);
}
__device__ __forceinline__ float bf2f(short s) {
    return __uint_as_float(((uint32_t)(uint16_t)s) << 16);
}

// ---------------------------------------------------------------------------
// K1: blocks 0..511 zero Sf; block 512 computes dinv.
// ---------------------------------------------------------------------------
__global__ __launch_bounds__(512) void prep_zero_dinv(const int* __restrict__ ecol,
                                                      float* __restrict__ Sf,
                                                      float* __restrict__ dinv) {
    const int b = blockIdx.x, t = threadIdx.x;
    if (b < 512) {
        Sf[b * 512 + t] = 0.0f;
    } else {
        __shared__ int sdeg[NUM];
        sdeg[t] = 0;
        __syncthreads();
        for (int e = t; e < NE; e += 512) atomicAdd(&sdeg[ecol[e]], 1);
        __syncthreads();
        int d = sdeg[t];
        dinv[t] = d > 0 ? rsqrtf((float)d) : 0.0f;
    }
}

// ---------------------------------------------------------------------------
// K2: scatter edge norms into dense Sf[c][r].
// ---------------------------------------------------------------------------
__global__ __launch_bounds__(512) void prep_scatter(const int* __restrict__ erow,
                                                    const int* __restrict__ ecol,
                                                    const float* __restrict__ dinv,
                                                    float* __restrict__ Sf) {
    int e = blockIdx.x * 512 + threadIdx.x;
    if (e < NE) {
        int r = erow[e], c = ecol[e];
        atomicAdd(&Sf[c * 512 + r], dinv[r] * dinv[c]);
    }
}

// ---------------------------------------------------------------------------
// K3: Sb = bf16(Sf); E1T[d][r] = (emb@W1)^T bf16; W2T[dout][d] = W2^T bf16.
// ---------------------------------------------------------------------------
__global__ __launch_bounds__(256) void prep_cast(const float* __restrict__ Sf,
                                                 const float* __restrict__ emb,
                                                 const float* __restrict__ W1,
                                                 const float* __restrict__ W2,
                                                 short* __restrict__ Sb,
                                                 short* __restrict__ E1T,
                                                 short* __restrict__ W2T) {
    int g = blockIdx.x * 256 + threadIdx.x;
    if (g < NUM * NUM) {
        Sb[g] = f2bf(Sf[g]);
    } else if (g < NUM * NUM + HD * NUM) {
        int j = g - NUM * NUM;
        int d = j >> 9, r = j & 511;
        float acc = 0.0f;
        #pragma unroll
        for (int k = 0; k < HD; ++k) acc += emb[r * HD + k] * W1[k * HD + d];
        E1T[j] = f2bf(acc);
    } else if (g < NUM * NUM + HD * NUM + HD * HD) {
        int j = g - NUM * NUM - HD * NUM;
        int dout = j >> 6, d = j & 63;
        W2T[j] = f2bf(W2[d * HD + dout]);
    }
}

// ---------------------------------------------------------------------------
// agg1: h1T[n][c] = relu( (S @ B1)[c,n] + b1[d(n)] ),  B1[r,n] = x[b(n),r]*E1[r,d(n)]
// Block tile 128(c) x 256(n=4 batches x 64 d), K=512 (r), BK=64.
// 8 waves as 2m x 4n; per-wave 64x64 (acc 4x4) -> 8 LDS reads / 16 MFMA per ks.
// ---------------------------------------------------------------------------
__global__ __launch_bounds__(512, 4) void agg1_gemm(
    const short* __restrict__ Sb, const short* __restrict__ E1T,
    const float* __restrict__ x, const float* __restrict__ b1,
    short* __restrict__ h1T, int b0)
{
    __shared__ short As[128 * 72];   // 18432 B  S tile [c][r]
    __shared__ short Bt[256 * 72];   // 36864 B  B1 tile [n][r]
    __shared__ float sb1[HD];

    const int t = threadIdx.x;
    const int ctile = blockIdx.x, ntile = blockIdx.y;
    const int lane = t & 63, wave = t >> 6;
    const int q = lane >> 4, l15 = lane & 15;
    const int wm = wave >> 2, wn = wave & 3;   // 2m x 4n wave grid
    const int bb = b0 + ntile * 4;             // 4 batches per tile

    if (t < HD) sb1[t] = b1[t];

    f32x4 acc[4][4];
    #pragma unroll
    for (int mt = 0; mt < 4; ++mt)
        #pragma unroll
        for (int nt = 0; nt < 4; ++nt) acc[mt][nt] = (f32x4){0.f, 0.f, 0.f, 0.f};

    for (int k0 = 0; k0 < NUM; k0 += 64) {
        __syncthreads();
        // stage A: S[ctile*128 + row][k0..k0+63]
        #pragma unroll
        for (int p = 0; p < 2; ++p) {
            int idx = t + p * 512;
            int row = idx >> 3, seg = (idx & 7) * 8;
            *(short8*)&As[row * 72 + seg] =
                *(const short8*)&Sb[(ctile * 128 + row) * NUM + k0 + seg];
        }
        // build B: Bt[n][r] = x[bb + n/64][k0+r] * E1T[n%64][k0+r]
        #pragma unroll
        for (int p = 0; p < 4; ++p) {
            int idx = t + p * 512;
            int n = idx >> 3, r8 = (idx & 7) * 8;
            int bloc = n >> 6, d = n & 63;
            short8 e = *(const short8*)&E1T[d * NUM + k0 + r8];
            const float* xp = &x[(bb + bloc) * NUM + k0 + r8];
            f32x4 x0 = *(const f32x4*)xp;
            f32x4 x1 = *(const f32x4*)(xp + 4);
            short8 o;
            o[0] = f2bf(x0[0] * bf2f(e[0])); o[1] = f2bf(x0[1] * bf2f(e[1]));
            o[2] = f2bf(x0[2] * bf2f(e[2])); o[3] = f2bf(x0[3] * bf2f(e[3]));
            o[4] = f2bf(x1[0] * bf2f(e[4])); o[5] = f2bf(x1[1] * bf2f(e[5]));
            o[6] = f2bf(x1[2] * bf2f(e[6])); o[7] = f2bf(x1[3] * bf2f(e[7]));
            *(short8*)&Bt[n * 72 + r8] = o;
        }
        __syncthreads();
        #pragma unroll
        for (int ks = 0; ks < 2; ++ks) {
            short8 af[4], bf_[4];
            #pragma unroll
            for (int mt = 0; mt < 4; ++mt)
                af[mt] = *(const short8*)&As[(wm * 64 + mt * 16 + l15) * 72 + ks * 32 + q * 8];
            #pragma unroll
            for (int nt = 0; nt < 4; ++nt)
                bf_[nt] = *(const short8*)&Bt[(wn * 64 + nt * 16 + l15) * 72 + ks * 32 + q * 8];
            #pragma unroll
            for (int mt = 0; mt < 4; ++mt)
                #pragma unroll
                for (int nt = 0; nt < 4; ++nt)
                    acc[mt][nt] = __builtin_amdgcn_mfma_f32_16x16x32_bf16(
                        af[mt], bf_[nt], acc[mt][nt], 0, 0, 0);
        }
    }
    // epilogue: relu(+b1) -> h1T[n][c] bf16
    #pragma unroll
    for (int nt = 0; nt < 4; ++nt) {
        int ncol = wn * 64 + nt * 16 + l15;
        float bv = sb1[ncol & 63];
        size_t nl = (size_t)(ntile * 256 + ncol);
        #pragma unroll
        for (int mt = 0; mt < 4; ++mt) {
            short4v o;
            #pragma unroll
            for (int i = 0; i < 4; ++i)
                o[i] = f2bf(fmaxf(acc[mt][nt][i] + bv, 0.0f));
            int c = ctile * 128 + wm * 64 + mt * 16 + q * 4;
            *(short4v*)&h1T[nl * NUM + c] = o;
        }
    }
}

// ---------------------------------------------------------------------------
// agg2: g2 = S @ h1; epilogue: t = relu(g2@W2 + b2) @ W3 via in-LDS T
// round-trip + second MFMA pass. Block tile 128(c) x 256(n=4 batches).
// ---------------------------------------------------------------------------
__global__ __launch_bounds__(512, 4) void agg2_gemm(
    const short* __restrict__ Sb, const short* __restrict__ h1T,
    const short* __restrict__ W2T, const float* __restrict__ b2,
    const float* __restrict__ W3, short* __restrict__ tglob, int b0)
{
    // region0: As(9216 sh) + Bt(18432 sh) = 27648 sh, overlapped by T(128x260 = 33280 sh)
    __shared__ short sm[33280 + 64 * 72];
    __shared__ float sb2[HD], sw3[HD];
    short* As  = sm;
    short* Bt  = sm + 9216;
    short* T   = sm;
    short* W2s = sm + 33280;

    const int t = threadIdx.x;
    const int ctile = blockIdx.x, ntile = blockIdx.y;
    const int lane = t & 63, wave = t >> 6;
    const int q = lane >> 4, l15 = lane & 15;
    const int wm = wave >> 2, wn = wave & 3;

    if (t < HD) { sb2[t] = b2[t]; sw3[t] = W3[t]; }
    // stage W2s[dout][d] (stride 72)
    {
        int row = t >> 3, seg = (t & 7) * 8;
        *(short8*)&W2s[row * 72 + seg] = *(const short8*)&W2T[row * HD + seg];
    }

    f32x4 acc[4][4];
    #pragma unroll
    for (int mt = 0; mt < 4; ++mt)
        #pragma unroll
        for (int nt = 0; nt < 4; ++nt) acc[mt][nt] = (f32x4){0.f, 0.f, 0.f, 0.f};

    for (int k0 = 0; k0 < NUM; k0 += 64) {
        __syncthreads();
        #pragma unroll
        for (int p = 0; p < 2; ++p) {
            int idx = t + p * 512;
            int row = idx >> 3, seg = (idx & 7) * 8;
            *(short8*)&As[row * 72 + seg] =
                *(const short8*)&Sb[(ctile * 128 + row) * NUM + k0 + seg];
        }
        #pragma unroll
        for (int p = 0; p < 4; ++p) {
            int idx = t + p * 512;
            int row = idx >> 3, seg = (idx & 7) * 8;
            *(short8*)&Bt[row * 72 + seg] =
                *(const short8*)&h1T[(size_t)(ntile * 256 + row) * NUM + k0 + seg];
        }
        __syncthreads();
        #pragma unroll
        for (int ks = 0; ks < 2; ++ks) {
            short8 af[4], bf_[4];
            #pragma unroll
            for (int mt = 0; mt < 4; ++mt)
                af[mt] = *(const short8*)&As[(wm * 64 + mt * 16 + l15) * 72 + ks * 32 + q * 8];
            #pragma unroll
            for (int nt = 0; nt < 4; ++nt)
                bf_[nt] = *(const short8*)&Bt[(wn * 64 + nt * 16 + l15) * 72 + ks * 32 + q * 8];
            #pragma unroll
            for (int mt = 0; mt < 4; ++mt)
                #pragma unroll
                for (int nt = 0; nt < 4; ++nt)
                    acc[mt][nt] = __builtin_amdgcn_mfma_f32_16x16x32_bf16(
                        af[mt], bf_[nt], acc[mt][nt], 0, 0, 0);
        }
    }
    // ---- round-trip g2 tile into LDS T[c][n] (stride 260), bf16
    __syncthreads();
    #pragma unroll
    for (int mt = 0; mt < 4; ++mt)
        #pragma unroll
        for (int nt = 0; nt < 4; ++nt)
            #pragma unroll
            for (int i = 0; i < 4; ++i)
                T[(wm * 64 + mt * 16 + q * 4 + i) * 260 + wn * 64 + nt * 16 + l15] =
                    f2bf(acc[mt][nt][i]);
    __syncthreads();

    // ---- U = T_b @ W2 per batch; t = relu(U+b2)@W3.
    // wave: bsel = w&3 (batch), cseg = w>>2 (64-c strip)
    {
        const int bsel = wave & 3;
        const int cseg = wave >> 2;
        f32x4 u[4][4];
        #pragma unroll
        for (int mt = 0; mt < 4; ++mt)
            #pragma unroll
            for (int nt = 0; nt < 4; ++nt) u[mt][nt] = (f32x4){0.f, 0.f, 0.f, 0.f};
        #pragma unroll
        for (int ks = 0; ks < 2; ++ks) {
            short8 af[4], bf_[4];
            #pragma unroll
            for (int mt = 0; mt < 4; ++mt)
                af[mt] = *(const short8*)&T[(cseg * 64 + mt * 16 + l15) * 260
                                            + bsel * 64 + ks * 32 + q * 8];
            #pragma unroll
            for (int nt = 0; nt < 4; ++nt)
                bf_[nt] = *(const short8*)&W2s[(nt * 16 + l15) * 72 + ks * 32 + q * 8];
            #pragma unroll
            for (int mt = 0; mt < 4; ++mt)
                #pragma unroll
                for (int nt = 0; nt < 4; ++nt)
                    u[mt][nt] = __builtin_amdgcn_mfma_f32_16x16x32_bf16(
                        af[mt], bf_[nt], u[mt][nt], 0, 0, 0);
        }
        // reduce over dout
        float p[4][4];
        #pragma unroll
        for (int mt = 0; mt < 4; ++mt)
            #pragma unroll
            for (int i = 0; i < 4; ++i) {
                float a = 0.0f;
                #pragma unroll
                for (int nt = 0; nt < 4; ++nt) {
                    int dout = nt * 16 + l15;
                    a += fmaxf(u[mt][nt][i] + sb2[dout], 0.0f) * sw3[dout];
                }
                p[mt][i] = a;
            }
        #pragma unroll
        for (int ofs = 1; ofs <= 8; ofs <<= 1)
            #pragma unroll
            for (int mt = 0; mt < 4; ++mt)
                #pragma unroll
                for (int i = 0; i < 4; ++i)
                    p[mt][i] += __shfl_xor(p[mt][i], ofs, 64);
        if (l15 == 0) {
            size_t bg = (size_t)(b0 + ntile * 4 + bsel);
            #pragma unroll
            for (int mt = 0; mt < 4; ++mt) {
                short4v o;
                #pragma unroll
                for (int i = 0; i < 4; ++i) o[i] = f2bf(p[mt][i]);
                int c = ctile * 128 + cseg * 64 + mt * 16 + q * 4;
                *(short4v*)&tglob[bg * NUM + c] = o;
            }
        }
    }
}

// ---------------------------------------------------------------------------
// final: logits = S @ t + b3 -> softmax rows [0,10) / sigmoid -> out[b][c] fp32
// ---------------------------------------------------------------------------
__global__ __launch_bounds__(512) void final_gemm(
    const short* __restrict__ Sb, const short* __restrict__ tglob,
    const float* __restrict__ b3p, float* __restrict__ out)
{
    __shared__ short As[128 * 72];
    __shared__ short Bt[128 * 72];

    const int t = threadIdx.x;
    const int ctile = blockIdx.x, btile = blockIdx.y;
    const int lane = t & 63, wave = t >> 6;
    const int q = lane >> 4, l15 = lane & 15;
    const int wm = wave >> 2, wn = wave & 3;

    f32x4 acc[4][2];
    #pragma unroll
    for (int mt = 0; mt < 4; ++mt)
        #pragma unroll
        for (int nt = 0; nt < 2; ++nt) acc[mt][nt] = (f32x4){0.f, 0.f, 0.f, 0.f};

    for (int k0 = 0; k0 < NUM; k0 += 64) {
        __syncthreads();
        #pragma unroll
        for (int p = 0; p < 2; ++p) {
            int idx = t + p * 512;
            int row = idx >> 3, seg = (idx & 7) * 8;
            *(short8*)&As[row * 72 + seg] =
                *(const short8*)&Sb[(ctile * 128 + row) * NUM + k0 + seg];
            *(short8*)&Bt[row * 72 + seg] =
                *(const short8*)&tglob[(size_t)(btile * 128 + row) * NUM + k0 + seg];
        }
        __syncthreads();
        #pragma unroll
        for (int ks = 0; ks < 2; ++ks) {
            short8 af[4], bf_[2];
            #pragma unroll
            for (int mt = 0; mt < 4; ++mt)
                af[mt] = *(const short8*)&As[(wm * 64 + mt * 16 + l15) * 72 + ks * 32 + q * 8];
            #pragma unroll
            for (int nt = 0; nt < 2; ++nt)
                bf_[nt] = *(const short8*)&Bt[(wn * 32 + nt * 16 + l15) * 72 + ks * 32 + q * 8];
            #pragma unroll
            for (int mt = 0; mt < 4; ++mt)
                #pragma unroll
                for (int nt = 0; nt < 2; ++nt)
                    acc[mt][nt] = __builtin_amdgcn_mfma_f32_16x16x32_bf16(
                        af[mt], bf_[nt], acc[mt][nt], 0, 0, 0);
        }
    }

    const float b3 = b3p[0];
    float mx[2] = {0.f, 0.f}, sm[2] = {0.f, 0.f};
    if (ctile == 0 && wm == 0) {
        #pragma unroll
        for (int nt = 0; nt < 2; ++nt) {
            float m = -1e30f;
            #pragma unroll
            for (int i = 0; i < 4; ++i) {
                int c = q * 4 + i;
                float l = acc[0][nt][i] + b3;
                m = (c < MAIN) ? fmaxf(m, l) : m;
            }
            m = fmaxf(m, __shfl_xor(m, 16, 64));
            m = fmaxf(m, __shfl_xor(m, 32, 64));
            float s = 0.0f;
            #pragma unroll
            for (int i = 0; i < 4; ++i) {
                int c = q * 4 + i;
                float l = acc[0][nt][i] + b3;
                s += (c < MAIN) ? __expf(l - m) : 0.0f;
            }
            s += __shfl_xor(s, 16, 64);
            s += __shfl_xor(s, 32, 64);
            mx[nt] = m; sm[nt] = s;
        }
    }
    #pragma unroll
    for (int nt = 0; nt < 2; ++nt) {
        size_t bcol = (size_t)(btile * 128 + wn * 32 + nt * 16 + l15);
        #pragma unroll
        for (int mt = 0; mt < 4; ++mt) {
            f32x4 o;
            #pragma unroll
            for (int i = 0; i < 4; ++i) {
                int c = ctile * 128 + wm * 64 + mt * 16 + q * 4 + i;
                float l = acc[mt][nt][i] + b3;
                o[i] = (c < MAIN) ? __expf(l - mx[nt]) / sm[nt]
                                  : 1.0f / (1.0f + __expf(-l));
            }
            *(f32x4*)&out[bcol * NUM + ctile * 128 + wm * 64 + mt * 16 + q * 4] = o;
        }
    }
}

// ---------------------------------------------------------------------------
extern "C" void kernel_launch(void* const* d_in, const int* in_sizes, int n_in,
                              void* d_out, int out_size, void* d_ws, size_t ws_size,
                              hipStream_t stream) {
    const float* x    = (const float*)d_in[0];
    const float* emb  = (const float*)d_in[1];
    const float* W1   = (const float*)d_in[2];
    const float* b1   = (const float*)d_in[3];
    const float* W2   = (const float*)d_in[4];
    const float* b2   = (const float*)d_in[5];
    const float* W3   = (const float*)d_in[6];
    const float* b3   = (const float*)d_in[7];
    const int*   erow = (const int*)d_in[8];
    const int*   ecol = (const int*)d_in[9];

    char* ws = (char*)d_ws;
    float* Sf   = (float*)ws;                     // [0, 1 MB)
    short* Sb   = (short*)(ws + 1048576);         // 512 KB
    short* E1T  = (short*)(ws + 1572864);         // 64 KB  [d][r]
    short* W2T  = (short*)(ws + 1638400);         // 8 KB   [dout][d]
    float* dinv = (float*)(ws + 1646592);         // 2 KB
    short* tg   = (short*)(ws + 1648640);         // 1 MB   t[b][r] bf16
    short* h1T  = (short*)(ws + 2697216);         // chunk: CB*64 rows x 512 bf16

    int CB = 1024;
    while ((size_t)CB * 65536 + 2697216 > ws_size && CB > 16) CB >>= 1;
    int nchunks = NB / CB;

    prep_zero_dinv<<<513, 512, 0, stream>>>(ecol, Sf, dinv);
    prep_scatter<<<8, 512, 0, stream>>>(erow, ecol, dinv, Sf);
    prep_cast<<<1168, 256, 0, stream>>>(Sf, emb, W1, W2, Sb, E1T, W2T);

    for (int c = 0; c < nchunks; ++c) {
        int b0 = c * CB;
        agg1_gemm<<<dim3(4, CB / 4), 512, 0, stream>>>(Sb, E1T, x, b1, h1T, b0);
        agg2_gemm<<<dim3(4, CB / 4), 512, 0, stream>>>(Sb, h1T, W2T, b2, W3, tg, b0);
    }
    final_gemm<<<dim3(4, 8), 512, 0, stream>>>(Sb, tg, b3, (float*)d_out);
}